// Round 11
// baseline (529.258 us; speedup 1.0000x reference)
//
#include <hip/hip_runtime.h>
#include <hip/hip_bf16.h>
#include <math.h>

#define NCH 32

typedef unsigned short ushort_t;
typedef unsigned int uint_t;

static __device__ __forceinline__ float bf2f(ushort_t b) {
    return __uint_as_float(((uint_t)b) << 16);
}
static __device__ __forceinline__ ushort_t f2bf(float f) {
    __hip_bfloat16 h = __float2bfloat16(f);   // round-to-nearest-even
    return *reinterpret_cast<ushort_t*>(&h);
}

// ===========================================================================
// FLAT pipeline (round-11):
//   r10 post-mortem: per-node scatter amplification is region-fill-rate
//   bound (100K x 64B regions evict before filling). Fix: two-stage sort —
//   coarse buckets (1563 x 4KB regions, fill 64x faster) then per-bucket
//   LDS counting sort writing one contiguous window per block.
//   Also: u stored bf16 (uh) — stats gather 128B/edge, ws ~27MB.
// ===========================================================================

// --- per-node uh, vh (both bf16): 32 lanes per node ------------------------
__global__ __launch_bounds__(256) void k_uv2b(
    const float* __restrict__ x, const float* __restrict__ W,
    ushort_t* __restrict__ uh, ushort_t* __restrict__ vh, int N)
{
    __shared__ float At[NCH * NCH];   // At[k*32+c] = W[c][k] - W[c][32+k]
    __shared__ float Bt[NCH * NCH];   // Bt[k*32+c] = W[c][32+k]
    for (int i = threadIdx.x; i < NCH * NCH; i += 256) {
        const int k = i >> 5, c = i & 31;
        const float w1 = W[c * 64 + k];
        const float w2 = W[c * 64 + 32 + k];
        At[i] = w1 - w2;
        Bt[i] = w2;
    }
    __syncthreads();

    const int n = blockIdx.x * 8 + (threadIdx.x >> 5);
    const int c = threadIdx.x & 31;
    if (n >= N) return;

    const float xc = x[(size_t)n * NCH + c];
    float su = 0.f, sv = 0.f;
#pragma unroll
    for (int k = 0; k < NCH; ++k) {
        const float xk = __shfl(xc, k, 32);
        su = fmaf(At[k * 32 + c], xk, su);
        sv = fmaf(Bt[k * 32 + c], xk, sv);
    }
    uh[(size_t)n * NCH + c] = f2bf(su);
    vh[(size_t)n * NCH + c] = f2bf(sv);
}

// --- flat stats: per-edge y = uh[s] + vh[t]; reg sum/ssq; fused histogram --
__global__ __launch_bounds__(256) void k_stats_flat(
    const ushort_t* __restrict__ uh, const ushort_t* __restrict__ vh,
    const int* __restrict__ srci, const int* __restrict__ tgti,
    int* __restrict__ cnt_n,
    float* __restrict__ partials, int E)
{
    float sum[NCH], ssq[NCH];
#pragma unroll
    for (int c = 0; c < NCH; ++c) { sum[c] = 0.f; ssq[c] = 0.f; }

    const int stride = gridDim.x * 256;
    for (int e = blockIdx.x * 256 + threadIdx.x; e < E; e += stride) {
        const int s = srci[e];
        const int t = tgti[e];
        atomicAdd(&cnt_n[s], 1);          // native int RMW, fire-and-forget
        const uint_t* __restrict__ pu = (const uint_t*)(uh + (size_t)s * NCH);
        const uint_t* __restrict__ pw = (const uint_t*)(vh + (size_t)t * NCH);
        uint_t ub[16], wb[16];
#pragma unroll
        for (int k = 0; k < 16; ++k) ub[k] = pu[k];
#pragma unroll
        for (int k = 0; k < 16; ++k) wb[k] = pw[k];
#pragma unroll
        for (int k = 0; k < 16; ++k) {
            const uint_t a2 = ub[k], w2 = wb[k];
            const float u0 = __uint_as_float((a2 & 0xFFFFu) << 16);
            const float u1 = __uint_as_float(a2 & 0xFFFF0000u);
            const float v0 = __uint_as_float((w2 & 0xFFFFu) << 16);
            const float v1 = __uint_as_float(w2 & 0xFFFF0000u);
            const int c0 = 2*k, c1 = 2*k + 1;
            const float y0 = u0 + v0;
            const float y1 = u1 + v1;
            sum[c0] += y0; ssq[c0] = fmaf(y0, y0, ssq[c0]);
            sum[c1] += y1; ssq[c1] = fmaf(y1, y1, ssq[c1]);
        }
    }

#pragma unroll
    for (int c = 0; c < NCH; ++c) {
#pragma unroll
        for (int off = 32; off > 0; off >>= 1) {
            sum[c] += __shfl_down(sum[c], off);
            ssq[c] += __shfl_down(ssq[c], off);
        }
    }
    __shared__ float red[4][64];
    const int lane = threadIdx.x & 63, wave = threadIdx.x >> 6;
    if (lane == 0) {
#pragma unroll
        for (int c = 0; c < NCH; ++c) { red[wave][c] = sum[c]; red[wave][NCH+c] = ssq[c]; }
    }
    __syncthreads();
    if (threadIdx.x < 64)
        partials[(size_t)blockIdx.x * 64 + threadIdx.x] =
            red[0][threadIdx.x] + red[1][threadIdx.x]
          + red[2][threadIdx.x] + red[3][threadIdx.x];
}

// --- scan pass 1: per-block (1024 elems) local exclusive scan + block sum --
__global__ __launch_bounds__(256) void k_scan1(
    const int* __restrict__ counts,
    int* __restrict__ offsets,
    int* __restrict__ blksum,
    int N)
{
    const int tid = threadIdx.x;
    const int base = blockIdx.x * 1024 + tid * 4;
    int c0 = 0, c1 = 0, c2 = 0, c3 = 0;
    if (base + 3 < N) {
        const int4 q = *(const int4*)(counts + base);
        c0 = q.x; c1 = q.y; c2 = q.z; c3 = q.w;
    } else {
        if (base + 0 < N) c0 = counts[base + 0];
        if (base + 1 < N) c1 = counts[base + 1];
        if (base + 2 < N) c2 = counts[base + 2];
        if (base + 3 < N) c3 = counts[base + 3];
    }
    const int tsum = c0 + c1 + c2 + c3;

    const int lane = tid & 63, wv = tid >> 6;
    int val = tsum;
#pragma unroll
    for (int off = 1; off < 64; off <<= 1) {
        int t = __shfl_up(val, off);
        if (lane >= off) val += t;
    }
    __shared__ int wsum[4];
    __shared__ int woff[4];
    if (lane == 63) wsum[wv] = val;
    __syncthreads();
    if (tid == 0) {
        int a = 0;
#pragma unroll
        for (int w = 0; w < 4; ++w) { woff[w] = a; a += wsum[w]; }
        blksum[blockIdx.x] = a;
    }
    __syncthreads();
    int run = woff[wv] + (val - tsum);
    if (base + 0 < N) { offsets[base + 0] = run; run += c0; }
    if (base + 1 < N) { offsets[base + 1] = run; run += c1; }
    if (base + 2 < N) { offsets[base + 2] = run; run += c2; }
    if (base + 3 < N) { offsets[base + 3] = run; }
}

// --- scan pass 2: exclusive scan of block sums (<=1024), in place ----------
__global__ __launch_bounds__(1024) void k_scan2(int* __restrict__ blksum, int NBLK)
{
    const int tid = threadIdx.x;
    int v = (tid < NBLK) ? blksum[tid] : 0;
    const int lane = tid & 63, wv = tid >> 6;
    int val = v;
#pragma unroll
    for (int off = 1; off < 64; off <<= 1) {
        int t = __shfl_up(val, off);
        if (lane >= off) val += t;
    }
    __shared__ int wsum[16];
    __shared__ int woff[16];
    if (lane == 63) wsum[wv] = val;
    __syncthreads();
    if (tid == 0) {
        int a = 0;
#pragma unroll
        for (int w = 0; w < 16; ++w) { woff[w] = a; a += wsum[w]; }
    }
    __syncthreads();
    if (tid < NBLK) blksum[tid] = woff[wv] + val - v;   // exclusive
}

// --- scan pass 3: finalize offsets; emit coarse-bucket cursors -------------
__global__ __launch_bounds__(256) void k_scan3(
    int* __restrict__ offsets, int* __restrict__ cur_b,
    const int* __restrict__ blksum, int N)
{
    const int i = blockIdx.x * 256 + threadIdx.x;
    if (i >= N) return;
    const int o = offsets[i] + blksum[i >> 10];
    offsets[i] = o;
    if ((i & 63) == 0) cur_b[i >> 6] = o;   // bucket b starts at node b<<6
}

// --- stage A: scatter edges into coarse buckets (src>>6) -------------------
// 1563 regions x ~4KB: fill rate 64x the per-node version -> sectors
// complete before L2 eviction (r10 theory).
__global__ __launch_bounds__(256) void k_binA(
    const int* __restrict__ srci, const int* __restrict__ tgti,
    int* __restrict__ cur_b, int* __restrict__ payload, int E)
{
    const int e = blockIdx.x * 256 + threadIdx.x;
    if (e >= E) return;
    const int s = srci[e];
    const int pos = atomicAdd(&cur_b[s >> 6], 1);
    payload[pos] = ((s & 63) << 17) | tgti[e];
}

// --- stage B: per-bucket LDS counting sort -> exact CSR tperm --------------
// Each block owns one contiguous ~4KB output window; LDS histogram of 64
// src-locals + wave scan gives in-bucket node offsets (== global CSR since
// bucket regions are contiguous and node-ordered).
__global__ __launch_bounds__(256) void k_binB(
    const int* __restrict__ payload, const int* __restrict__ off_n,
    int* __restrict__ tperm, int N, int E)
{
    __shared__ int h[64];
    __shared__ int cur[64];
    const int b = blockIdx.x;
    const int boff = off_n[b << 6];
    const int nxt = (b + 1) << 6;
    const int bend = (nxt < N) ? off_n[nxt] : E;
    const int bcnt = bend - boff;

    if (threadIdx.x < 64) h[threadIdx.x] = 0;
    __syncthreads();
    for (int i = threadIdx.x; i < bcnt; i += 256)
        atomicAdd(&h[(payload[boff + i] >> 17) & 63], 1);
    __syncthreads();
    if (threadIdx.x < 64) {
        const int v = h[threadIdx.x];
        int val = v;
#pragma unroll
        for (int off = 1; off < 64; off <<= 1) {
            int t = __shfl_up(val, off);
            if (threadIdx.x >= (uint_t)off) val += t;
        }
        cur[threadIdx.x] = boff + (val - v);   // bucket-base + exclusive scan
    }
    __syncthreads();
    for (int i = threadIdx.x; i < bcnt; i += 256) {
        const int w = payload[boff + i];       // L2-hot second read
        const int pos = atomicAdd(&cur[(w >> 17) & 63], 1);
        tperm[pos] = w & 0x1FFFF;
    }
}

// --- combine partials -> BN affine a,b -------------------------------------
__global__ __launch_bounds__(256) void k_finalize(
    const float* __restrict__ partials, int nblocks,
    const float* __restrict__ gamma, const float* __restrict__ beta,
    float* __restrict__ ab, float invE)
{
    __shared__ float acc[4][64];
    const int vtx = threadIdx.x & 63, chunk = threadIdx.x >> 6;
    float s = 0.f;
    for (int r = chunk; r < nblocks; r += 4) s += partials[(size_t)r * 64 + vtx];
    acc[chunk][vtx] = s;
    __syncthreads();
    if (threadIdx.x < 64) acc[0][vtx] = acc[0][vtx] + acc[1][vtx] + acc[2][vtx] + acc[3][vtx];
    __syncthreads();
    if (threadIdx.x < 32) {
        const int c = threadIdx.x;
        float mean = acc[0][c] * invE;
        float var  = acc[0][32 + c] * invE - mean * mean;
        float rstd = rsqrtf(var + 1e-5f);
        float a = gamma[c] * rstd;
        ab[c] = a; ab[32 + c] = beta[c] - mean * a;
    }
}

// --- per-node apply: 32-lane group per node, register accumulate -----------
__global__ __launch_bounds__(256) void k_apply_node(
    const ushort_t* __restrict__ uh, const ushort_t* __restrict__ vh,
    const int* __restrict__ tperm, const int* __restrict__ off_n,
    const int* __restrict__ cnt_n, const float* __restrict__ ab,
    float* __restrict__ out, int N)
{
    const int n = blockIdx.x * 8 + (threadIdx.x >> 5);
    const int c = threadIdx.x & 31;
    if (n >= N) return;

    const int off = off_n[n];
    const int deg = cnt_n[n];
    const float un  = bf2f(uh[(size_t)n * NCH + c]);
    const float a_c = ab[c];
    const float b_c = ab[32 + c];

    float acc = 0.f;
    int i = 0;
    for (; i + 4 <= deg; i += 4) {
        int t0 = tperm[off + i + 0];
        int t1 = tperm[off + i + 1];
        int t2 = tperm[off + i + 2];
        int t3 = tperm[off + i + 3];
        ushort_t v0 = vh[(size_t)t0 * NCH + c];
        ushort_t v1 = vh[(size_t)t1 * NCH + c];
        ushort_t v2 = vh[(size_t)t2 * NCH + c];
        ushort_t v3 = vh[(size_t)t3 * NCH + c];
        float z0 = fmaf(a_c, un + bf2f(v0), b_c);
        float z1 = fmaf(a_c, un + bf2f(v1), b_c);
        float z2 = fmaf(a_c, un + bf2f(v2), b_c);
        float z3 = fmaf(a_c, un + bf2f(v3), b_c);
        z0 = (z0 > 0.f) ? z0 : (__expf(z0) - 1.0f);
        z1 = (z1 > 0.f) ? z1 : (__expf(z1) - 1.0f);
        z2 = (z2 > 0.f) ? z2 : (__expf(z2) - 1.0f);
        z3 = (z3 > 0.f) ? z3 : (__expf(z3) - 1.0f);
        acc += (z0 + z1) + (z2 + z3);
    }
    for (; i < deg; ++i) {
        int t = tperm[off + i];
        float z = fmaf(a_c, un + bf2f(vh[(size_t)t * NCH + c]), b_c);
        z = (z > 0.f) ? z : (__expf(z) - 1.0f);
        acc += z;
    }
    out[(size_t)n * NCH + c] = acc;
}

// ===========================================================================
// FALLBACK (round-1 proven path) — only if ws too small
// ===========================================================================
__global__ __launch_bounds__(256) void k_stats_hist(
    const float* __restrict__ x,
    const int* __restrict__ srci, const int* __restrict__ tgti,
    const float* __restrict__ W,
    float* __restrict__ partials, int E)
{
    float sum[NCH], ssq[NCH];
#pragma unroll
    for (int c = 0; c < NCH; ++c) { sum[c] = 0.f; ssq[c] = 0.f; }
    const int stride = gridDim.x * blockDim.x;
    for (int e = blockIdx.x * blockDim.x + threadIdx.x; e < E; e += stride) {
        const int s = srci[e], t = tgti[e];
        const float4* ps = (const float4*)(x + (size_t)s * NCH);
        const float4* pt = (const float4*)(x + (size_t)t * NCH);
        float xs[NCH], dx[NCH];
#pragma unroll
        for (int i = 0; i < 8; ++i) {
            float4 a = ps[i], bb = pt[i];
            xs[4*i+0] = a.x; xs[4*i+1] = a.y; xs[4*i+2] = a.z; xs[4*i+3] = a.w;
            dx[4*i+0] = bb.x - a.x; dx[4*i+1] = bb.y - a.y;
            dx[4*i+2] = bb.z - a.z; dx[4*i+3] = bb.w - a.w;
        }
#pragma unroll
        for (int c = 0; c < NCH; ++c) {
            const float* wr = W + c * 64;
            float y = 0.f;
#pragma unroll
            for (int k = 0; k < NCH; ++k) y = fmaf(wr[k], xs[k], y);
#pragma unroll
            for (int k = 0; k < NCH; ++k) y = fmaf(wr[32 + k], dx[k], y);
            sum[c] += y;
            ssq[c] = fmaf(y, y, ssq[c]);
        }
    }
#pragma unroll
    for (int c = 0; c < NCH; ++c) {
#pragma unroll
        for (int off = 32; off > 0; off >>= 1) {
            sum[c] += __shfl_down(sum[c], off);
            ssq[c] += __shfl_down(ssq[c], off);
        }
    }
    __shared__ float red[4][64];
    const int lane = threadIdx.x & 63, wave = threadIdx.x >> 6;
    if (lane == 0) {
#pragma unroll
        for (int c = 0; c < NCH; ++c) { red[wave][c] = sum[c]; red[wave][NCH+c] = ssq[c]; }
    }
    __syncthreads();
    if (threadIdx.x < 64)
        partials[(size_t)blockIdx.x * 64 + threadIdx.x] =
            red[0][threadIdx.x] + red[1][threadIdx.x] + red[2][threadIdx.x] + red[3][threadIdx.x];
}

__global__ __launch_bounds__(256) void k_apply_atomic(
    const float* __restrict__ x,
    const int* __restrict__ srci, const int* __restrict__ tgti,
    const float* __restrict__ W, const float* __restrict__ ab,
    float* __restrict__ out, int E)
{
    const int e = blockIdx.x * 256 + threadIdx.x;
    if (e >= E) return;
    const int s = srci[e], t = tgti[e];
    const float4* ps = (const float4*)(x + (size_t)s * NCH);
    const float4* pt = (const float4*)(x + (size_t)t * NCH);
    float xs[NCH], dx[NCH];
#pragma unroll
    for (int i = 0; i < 8; ++i) {
        float4 a = ps[i], bb = pt[i];
        xs[4*i+0] = a.x; xs[4*i+1] = a.y; xs[4*i+2] = a.z; xs[4*i+3] = a.w;
        dx[4*i+0] = bb.x - a.x; dx[4*i+1] = bb.y - a.y;
        dx[4*i+2] = bb.z - a.z; dx[4*i+3] = bb.w - a.w;
    }
    float* orow = out + (size_t)s * NCH;
#pragma unroll
    for (int c = 0; c < NCH; ++c) {
        const float* wr = W + c * 64;
        float y = 0.f;
#pragma unroll
        for (int k = 0; k < NCH; ++k) y = fmaf(wr[k], xs[k], y);
#pragma unroll
        for (int k = 0; k < NCH; ++k) y = fmaf(wr[32 + k], dx[k], y);
        float z = fmaf(ab[c], y, ab[32 + c]);
        z = (z > 0.f) ? z : (__expf(z) - 1.0f);
        atomicAdd(orow + c, z);
    }
}

// ===========================================================================
extern "C" void kernel_launch(void* const* d_in, const int* in_sizes, int n_in,
                              void* d_out, int out_size, void* d_ws, size_t ws_size,
                              hipStream_t stream)
{
    const float* x     = (const float*)d_in[0];
    const int*   ei    = (const int*)d_in[1];
    const float* W     = (const float*)d_in[2];
    const float* gamma = (const float*)d_in[3];
    const float* beta  = (const float*)d_in[4];
    const int E = in_sizes[1] / 2;
    const int N = in_sizes[0] / NCH;
    const int* srci = ei;
    const int* tgti = ei + E;

    const int SB = 512;                   // stats grid
    const int NBLK = (N + 1023) / 1024;   // scan pass-1 blocks (<=1024)
    const int NB = (N + 63) >> 6;         // coarse buckets

    // ws: uh[N*32]bf16 | vh[N*32]bf16 | tperm[E] | payload[E]
    //     | cnt_n[N] off_n[N] | cur_b[NB pad] blksum[1024]
    //     | partials[SB*64]f32 | ab[64]f32
    size_t need = (size_t)N * NCH * 2 * 2
                + ((size_t)E * 2 + 2 * (size_t)N + (size_t)NB + 1024) * 4
                + ((size_t)SB * 64 + 64) * 4;

    if (NBLK <= 1024 && ws_size >= need) {
        ushort_t* uh      = (ushort_t*)d_ws;
        ushort_t* vh      = uh + (size_t)N * NCH;
        int*      tperm   = (int*)(vh + (size_t)N * NCH);
        int*      payload = tperm + E;
        int*      cnt_n   = payload + E;
        int*      off_n   = cnt_n + N;
        int*      cur_b   = off_n + N;
        int*      blksum  = cur_b + NB;
        float*    partials= (float*)(blksum + 1024);
        float*    ab      = partials + (size_t)SB * 64;

        hipMemsetAsync(cnt_n, 0, (size_t)N * sizeof(int), stream);
        k_uv2b<<<(N + 7) / 8, 256, 0, stream>>>(x, W, uh, vh, N);
        k_stats_flat<<<SB, 256, 0, stream>>>(uh, vh, srci, tgti, cnt_n, partials, E);
        k_scan1<<<NBLK, 256, 0, stream>>>(cnt_n, off_n, blksum, N);
        k_scan2<<<1, 1024, 0, stream>>>(blksum, NBLK);
        k_scan3<<<(N + 255) / 256, 256, 0, stream>>>(off_n, cur_b, blksum, N);
        k_binA<<<(E + 255) / 256, 256, 0, stream>>>(srci, tgti, cur_b, payload, E);
        k_binB<<<NB, 256, 0, stream>>>(payload, off_n, tperm, N, E);
        k_finalize<<<1, 256, 0, stream>>>(partials, SB, gamma, beta, ab, 1.0f / (float)E);
        k_apply_node<<<(N + 7) / 8, 256, 0, stream>>>(uh, vh, tperm, off_n, cnt_n, ab,
                                                      (float*)d_out, N);
    } else {
        const int SBf = 512;
        float* ab       = (float*)d_ws;
        float* partials = ab + 64;
        hipMemsetAsync(d_out, 0, (size_t)out_size * sizeof(float), stream);
        k_stats_hist<<<SBf, 256, 0, stream>>>(x, srci, tgti, W, partials, E);
        k_finalize<<<1, 256, 0, stream>>>(partials, SBf, gamma, beta, ab, 1.0f / (float)E);
        k_apply_atomic<<<(E + 255) / 256, 256, 0, stream>>>(x, srci, tgti, W, ab,
                                                            (float*)d_out, E);
    }
}

// Round 12
// 408.506 us; speedup vs baseline: 1.2956x; 1.2956x over previous
//
#include <hip/hip_runtime.h>
#include <hip/hip_bf16.h>
#include <math.h>

#define NCH 32

typedef unsigned short ushort_t;
typedef unsigned int uint_t;

static __device__ __forceinline__ float bf2f(ushort_t b) {
    return __uint_as_float(((uint_t)b) << 16);
}
static __device__ __forceinline__ ushort_t f2bf(float f) {
    __hip_bfloat16 h = __float2bfloat16(f);   // round-to-nearest-even
    return *reinterpret_cast<ushort_t*>(&h);
}

// ===========================================================================
// Round-12: NO SORT. r11 post-mortem: any fine-grained global scatter from a
// full-chip grid costs ~10x write amplification (cross-XCD partial-sector
// copies) + cursor atomics. So the counting sort is gone entirely.
//   u = (W1-W2)x, v = W2 x (both bf16);  y_e = u[src] + v[tgt]
//   stats: 32-lane group per edge (2 acc/lane -> low VGPR, high occupancy)
//   apply: group per edge, BN-affine+ELU, native global_atomic_add_f32
//          (fire-and-forget; r1's 2.6ms was the CAS-loop safe atomic,
//           a different instruction class entirely)
// 5 dispatches total.
// ===========================================================================

// --- per-node uh, vh (both bf16): 32 lanes per node ------------------------
__global__ __launch_bounds__(256) void k_uv2b(
    const float* __restrict__ x, const float* __restrict__ W,
    ushort_t* __restrict__ uh, ushort_t* __restrict__ vh, int N)
{
    __shared__ float At[NCH * NCH];   // At[k*32+c] = W[c][k] - W[c][32+k]
    __shared__ float Bt[NCH * NCH];   // Bt[k*32+c] = W[c][32+k]
    for (int i = threadIdx.x; i < NCH * NCH; i += 256) {
        const int k = i >> 5, c = i & 31;
        const float w1 = W[c * 64 + k];
        const float w2 = W[c * 64 + 32 + k];
        At[i] = w1 - w2;
        Bt[i] = w2;
    }
    __syncthreads();

    const int n = blockIdx.x * 8 + (threadIdx.x >> 5);
    const int c = threadIdx.x & 31;
    if (n >= N) return;

    const float xc = x[(size_t)n * NCH + c];
    float su = 0.f, sv = 0.f;
#pragma unroll
    for (int k = 0; k < NCH; ++k) {
        const float xk = __shfl(xc, k, 32);
        su = fmaf(At[k * 32 + c], xk, su);
        sv = fmaf(Bt[k * 32 + c], xk, sv);
    }
    uh[(size_t)n * NCH + c] = f2bf(su);
    vh[(size_t)n * NCH + c] = f2bf(sv);
}

// --- stats: 32-lane group per edge, 4-edge batches, 2 accumulators/lane ----
__global__ __launch_bounds__(256) void k_stats_g(
    const ushort_t* __restrict__ uh, const ushort_t* __restrict__ vh,
    const int* __restrict__ srci, const int* __restrict__ tgti,
    float* __restrict__ partials, int E)
{
    const int c  = threadIdx.x & 31;
    const int g  = (blockIdx.x * 256 + threadIdx.x) >> 5;
    const int nG = (gridDim.x * 256) >> 5;

    float sum = 0.f, ssq = 0.f;
    int e = g;
    for (; e + 3 * nG < E; e += 4 * nG) {
        const int e0 = e, e1 = e + nG, e2 = e + 2 * nG, e3 = e + 3 * nG;
        const int s0 = srci[e0], s1 = srci[e1], s2 = srci[e2], s3 = srci[e3];
        const int t0 = tgti[e0], t1 = tgti[e1], t2 = tgti[e2], t3 = tgti[e3];
        const ushort_t a0 = uh[(size_t)s0 * NCH + c];
        const ushort_t a1 = uh[(size_t)s1 * NCH + c];
        const ushort_t a2 = uh[(size_t)s2 * NCH + c];
        const ushort_t a3 = uh[(size_t)s3 * NCH + c];
        const ushort_t b0 = vh[(size_t)t0 * NCH + c];
        const ushort_t b1 = vh[(size_t)t1 * NCH + c];
        const ushort_t b2 = vh[(size_t)t2 * NCH + c];
        const ushort_t b3 = vh[(size_t)t3 * NCH + c];
        const float y0 = bf2f(a0) + bf2f(b0);
        const float y1 = bf2f(a1) + bf2f(b1);
        const float y2 = bf2f(a2) + bf2f(b2);
        const float y3 = bf2f(a3) + bf2f(b3);
        sum += (y0 + y1) + (y2 + y3);
        ssq = fmaf(y0, y0, ssq); ssq = fmaf(y1, y1, ssq);
        ssq = fmaf(y2, y2, ssq); ssq = fmaf(y3, y3, ssq);
    }
    for (; e < E; e += nG) {
        const int s = srci[e], t = tgti[e];
        const float y = bf2f(uh[(size_t)s * NCH + c]) + bf2f(vh[(size_t)t * NCH + c]);
        sum += y;
        ssq = fmaf(y, y, ssq);
    }

    __shared__ float sred[8][32];
    __shared__ float qred[8][32];
    const int lg = threadIdx.x >> 5;
    sred[lg][c] = sum;
    qred[lg][c] = ssq;
    __syncthreads();
    if (threadIdx.x < 32) {
        float a = 0.f;
#pragma unroll
        for (int q = 0; q < 8; ++q) a += sred[q][threadIdx.x];
        partials[(size_t)blockIdx.x * 64 + threadIdx.x] = a;
    } else if (threadIdx.x < 64) {
        const int cc = threadIdx.x - 32;
        float a = 0.f;
#pragma unroll
        for (int q = 0; q < 8; ++q) a += qred[q][cc];
        partials[(size_t)blockIdx.x * 64 + 32 + cc] = a;
    }
}

// --- combine partials -> BN affine a,b -------------------------------------
__global__ __launch_bounds__(256) void k_finalize(
    const float* __restrict__ partials, int nblocks,
    const float* __restrict__ gamma, const float* __restrict__ beta,
    float* __restrict__ ab, float invE)
{
    __shared__ float acc[4][64];
    const int vtx = threadIdx.x & 63, chunk = threadIdx.x >> 6;
    float s = 0.f;
    for (int r = chunk; r < nblocks; r += 4) s += partials[(size_t)r * 64 + vtx];
    acc[chunk][vtx] = s;
    __syncthreads();
    if (threadIdx.x < 64) acc[0][vtx] = acc[0][vtx] + acc[1][vtx] + acc[2][vtx] + acc[3][vtx];
    __syncthreads();
    if (threadIdx.x < 32) {
        const int c = threadIdx.x;
        float mean = acc[0][c] * invE;
        float var  = acc[0][32 + c] * invE - mean * mean;
        float rstd = rsqrtf(var + 1e-5f);
        float a = gamma[c] * rstd;
        ab[c] = a; ab[32 + c] = beta[c] - mean * a;
    }
}

// --- apply: group per edge, native global fp32 atomic scatter --------------
__global__ __launch_bounds__(256) void k_apply_edge(
    const ushort_t* __restrict__ uh, const ushort_t* __restrict__ vh,
    const int* __restrict__ srci, const int* __restrict__ tgti,
    const float* __restrict__ ab,
    float* __restrict__ out, int E)
{
    const int c  = threadIdx.x & 31;
    const float a_c = ab[c];
    const float b_c = ab[32 + c];
    const int g  = (blockIdx.x * 256 + threadIdx.x) >> 5;
    const int nG = (gridDim.x * 256) >> 5;

    int e = g;
    for (; e + 3 * nG < E; e += 4 * nG) {
        const int e0 = e, e1 = e + nG, e2 = e + 2 * nG, e3 = e + 3 * nG;
        const int s0 = srci[e0], s1 = srci[e1], s2 = srci[e2], s3 = srci[e3];
        const int t0 = tgti[e0], t1 = tgti[e1], t2 = tgti[e2], t3 = tgti[e3];
        const ushort_t a0 = uh[(size_t)s0 * NCH + c];
        const ushort_t a1 = uh[(size_t)s1 * NCH + c];
        const ushort_t a2 = uh[(size_t)s2 * NCH + c];
        const ushort_t a3 = uh[(size_t)s3 * NCH + c];
        const ushort_t v0 = vh[(size_t)t0 * NCH + c];
        const ushort_t v1 = vh[(size_t)t1 * NCH + c];
        const ushort_t v2 = vh[(size_t)t2 * NCH + c];
        const ushort_t v3 = vh[(size_t)t3 * NCH + c];
        float z0 = fmaf(a_c, bf2f(a0) + bf2f(v0), b_c);
        float z1 = fmaf(a_c, bf2f(a1) + bf2f(v1), b_c);
        float z2 = fmaf(a_c, bf2f(a2) + bf2f(v2), b_c);
        float z3 = fmaf(a_c, bf2f(a3) + bf2f(v3), b_c);
        z0 = (z0 > 0.f) ? z0 : (__expf(z0) - 1.0f);
        z1 = (z1 > 0.f) ? z1 : (__expf(z1) - 1.0f);
        z2 = (z2 > 0.f) ? z2 : (__expf(z2) - 1.0f);
        z3 = (z3 > 0.f) ? z3 : (__expf(z3) - 1.0f);
        unsafeAtomicAdd(&out[(size_t)s0 * NCH + c], z0);   // global_atomic_add_f32
        unsafeAtomicAdd(&out[(size_t)s1 * NCH + c], z1);
        unsafeAtomicAdd(&out[(size_t)s2 * NCH + c], z2);
        unsafeAtomicAdd(&out[(size_t)s3 * NCH + c], z3);
    }
    for (; e < E; e += nG) {
        const int s = srci[e], t = tgti[e];
        float z = fmaf(a_c, bf2f(uh[(size_t)s * NCH + c]) + bf2f(vh[(size_t)t * NCH + c]), b_c);
        z = (z > 0.f) ? z : (__expf(z) - 1.0f);
        unsafeAtomicAdd(&out[(size_t)s * NCH + c], z);
    }
}

// ===========================================================================
// FALLBACK (round-1 proven path) — only if ws too small
// ===========================================================================
__global__ __launch_bounds__(256) void k_stats_hist(
    const float* __restrict__ x,
    const int* __restrict__ srci, const int* __restrict__ tgti,
    const float* __restrict__ W,
    float* __restrict__ partials, int E)
{
    float sum[NCH], ssq[NCH];
#pragma unroll
    for (int c = 0; c < NCH; ++c) { sum[c] = 0.f; ssq[c] = 0.f; }
    const int stride = gridDim.x * blockDim.x;
    for (int e = blockIdx.x * blockDim.x + threadIdx.x; e < E; e += stride) {
        const int s = srci[e], t = tgti[e];
        const float4* ps = (const float4*)(x + (size_t)s * NCH);
        const float4* pt = (const float4*)(x + (size_t)t * NCH);
        float xs[NCH], dx[NCH];
#pragma unroll
        for (int i = 0; i < 8; ++i) {
            float4 a = ps[i], bb = pt[i];
            xs[4*i+0] = a.x; xs[4*i+1] = a.y; xs[4*i+2] = a.z; xs[4*i+3] = a.w;
            dx[4*i+0] = bb.x - a.x; dx[4*i+1] = bb.y - a.y;
            dx[4*i+2] = bb.z - a.z; dx[4*i+3] = bb.w - a.w;
        }
#pragma unroll
        for (int c = 0; c < NCH; ++c) {
            const float* wr = W + c * 64;
            float y = 0.f;
#pragma unroll
            for (int k = 0; k < NCH; ++k) y = fmaf(wr[k], xs[k], y);
#pragma unroll
            for (int k = 0; k < NCH; ++k) y = fmaf(wr[32 + k], dx[k], y);
            sum[c] += y;
            ssq[c] = fmaf(y, y, ssq[c]);
        }
    }
#pragma unroll
    for (int c = 0; c < NCH; ++c) {
#pragma unroll
        for (int off = 32; off > 0; off >>= 1) {
            sum[c] += __shfl_down(sum[c], off);
            ssq[c] += __shfl_down(ssq[c], off);
        }
    }
    __shared__ float red[4][64];
    const int lane = threadIdx.x & 63, wave = threadIdx.x >> 6;
    if (lane == 0) {
#pragma unroll
        for (int c = 0; c < NCH; ++c) { red[wave][c] = sum[c]; red[wave][NCH+c] = ssq[c]; }
    }
    __syncthreads();
    if (threadIdx.x < 64)
        partials[(size_t)blockIdx.x * 64 + threadIdx.x] =
            red[0][threadIdx.x] + red[1][threadIdx.x] + red[2][threadIdx.x] + red[3][threadIdx.x];
}

__global__ __launch_bounds__(256) void k_apply_atomic(
    const float* __restrict__ x,
    const int* __restrict__ srci, const int* __restrict__ tgti,
    const float* __restrict__ W, const float* __restrict__ ab,
    float* __restrict__ out, int E)
{
    const int e = blockIdx.x * 256 + threadIdx.x;
    if (e >= E) return;
    const int s = srci[e], t = tgti[e];
    const float4* ps = (const float4*)(x + (size_t)s * NCH);
    const float4* pt = (const float4*)(x + (size_t)t * NCH);
    float xs[NCH], dx[NCH];
#pragma unroll
    for (int i = 0; i < 8; ++i) {
        float4 a = ps[i], bb = pt[i];
        xs[4*i+0] = a.x; xs[4*i+1] = a.y; xs[4*i+2] = a.z; xs[4*i+3] = a.w;
        dx[4*i+0] = bb.x - a.x; dx[4*i+1] = bb.y - a.y;
        dx[4*i+2] = bb.z - a.z; dx[4*i+3] = bb.w - a.w;
    }
    float* orow = out + (size_t)s * NCH;
#pragma unroll
    for (int c = 0; c < NCH; ++c) {
        const float* wr = W + c * 64;
        float y = 0.f;
#pragma unroll
        for (int k = 0; k < NCH; ++k) y = fmaf(wr[k], xs[k], y);
#pragma unroll
        for (int k = 0; k < NCH; ++k) y = fmaf(wr[32 + k], dx[k], y);
        float z = fmaf(ab[c], y, ab[32 + c]);
        z = (z > 0.f) ? z : (__expf(z) - 1.0f);
        atomicAdd(orow + c, z);
    }
}

// ===========================================================================
extern "C" void kernel_launch(void* const* d_in, const int* in_sizes, int n_in,
                              void* d_out, int out_size, void* d_ws, size_t ws_size,
                              hipStream_t stream)
{
    const float* x     = (const float*)d_in[0];
    const int*   ei    = (const int*)d_in[1];
    const float* W     = (const float*)d_in[2];
    const float* gamma = (const float*)d_in[3];
    const float* beta  = (const float*)d_in[4];
    const int E = in_sizes[1] / 2;
    const int N = in_sizes[0] / NCH;
    const int* srci = ei;
    const int* tgti = ei + E;

    const int SB = 1024;   // stats grid (8192 groups)
    const int AB = 2048;   // apply grid (16384 groups)

    // ws: uh[N*32]bf16 | vh[N*32]bf16 | partials[SB*64]f32 | ab[64]f32
    size_t need = (size_t)N * NCH * 2 * 2
                + ((size_t)SB * 64 + 64) * 4;

    if (ws_size >= need) {
        ushort_t* uh      = (ushort_t*)d_ws;
        ushort_t* vh      = uh + (size_t)N * NCH;
        float*    partials= (float*)(vh + (size_t)N * NCH);
        float*    ab      = partials + (size_t)SB * 64;

        hipMemsetAsync(d_out, 0, (size_t)out_size * sizeof(float), stream);
        k_uv2b<<<(N + 7) / 8, 256, 0, stream>>>(x, W, uh, vh, N);
        k_stats_g<<<SB, 256, 0, stream>>>(uh, vh, srci, tgti, partials, E);
        k_finalize<<<1, 256, 0, stream>>>(partials, SB, gamma, beta, ab, 1.0f / (float)E);
        k_apply_edge<<<AB, 256, 0, stream>>>(uh, vh, srci, tgti, ab, (float*)d_out, E);
    } else {
        const int SBf = 512;
        float* ab       = (float*)d_ws;
        float* partials = ab + 64;
        hipMemsetAsync(d_out, 0, (size_t)out_size * sizeof(float), stream);
        k_stats_hist<<<SBf, 256, 0, stream>>>(x, srci, tgti, W, partials, E);
        k_finalize<<<1, 256, 0, stream>>>(partials, SBf, gamma, beta, ab, 1.0f / (float)E);
        k_apply_atomic<<<(E + 255) / 256, 256, 0, stream>>>(x, srci, tgti, W, ab,
                                                            (float*)d_out, E);
    }
}

// Round 13
// 307.605 us; speedup vs baseline: 1.7206x; 1.3280x over previous
//
#include <hip/hip_runtime.h>
#include <hip/hip_bf16.h>
#include <math.h>

#define NCH 32

typedef unsigned short ushort_t;
typedef unsigned int uint_t;
typedef unsigned char uchar_t;

static __device__ __forceinline__ float bf2f(ushort_t b) {
    return __uint_as_float(((uint_t)b) << 16);
}
static __device__ __forceinline__ ushort_t f2bf(float f) {
    __hip_bfloat16 h = __float2bfloat16(f);
    return *reinterpret_cast<ushort_t*>(&h);
}

using f32x2 = __attribute__((ext_vector_type(2))) float;

// --- packed bf16 global atomic with compile-safe fallback ------------------
// Preferred: unsafeAtomicAdd(__hip_bfloat162*) -> global_atomic_pk_add_bf16.
// If the overload doesn't exist in this ROCm, SFINAE picks a CAS loop
// (correct but slow) instead of failing to compile.
template <typename T>
__device__ __forceinline__ auto pkAddImpl(T* p, T v, int)
    -> decltype(unsafeAtomicAdd(p, v), void()) {
    unsafeAtomicAdd(p, v);
}
template <typename T>
__device__ void pkAddImpl(T* p, T v, long) {
    uint_t* q = reinterpret_cast<uint_t*>(p);
    uint_t vv = *reinterpret_cast<uint_t*>(&v);
    uint_t cur = *q;
    while (true) {
        float lo = bf2f((ushort_t)(cur & 0xFFFF)) + bf2f((ushort_t)(vv & 0xFFFF));
        float hi = bf2f((ushort_t)(cur >> 16)) + bf2f((ushort_t)(vv >> 16));
        uint_t nw = (uint_t)f2bf(lo) | ((uint_t)f2bf(hi) << 16);
        uint_t prev = atomicCAS(q, cur, nw);
        if (prev == cur) break;
        cur = prev;
    }
}
static __device__ __forceinline__ void pkAdd(__hip_bfloat162* p, float z0, float z1) {
    __hip_bfloat162 v;
    v.x = __float2bfloat16(z0);
    v.y = __float2bfloat16(z1);
    pkAddImpl(p, v, 0);
}

// ===========================================================================
// Round-13:
//   r12 post-mortem: apply is traffic-bound (FETCH 173MB gathers + WRITE
//   200MB = 4B per atomic). Levers: (1) pk bf16 atomics halve the atomic
//   count; (2) fp8 shadow copy of u/v halves stats gather bytes and shrinks
//   the random working set to ~6.4MB (per-XCD-L2-friendly).
// ===========================================================================

// --- per-node uh,vh (bf16) + uq,vq (fp8 e4m3): 32 lanes per node -----------
__global__ __launch_bounds__(256) void k_uv3(
    const float* __restrict__ x, const float* __restrict__ W,
    ushort_t* __restrict__ uh, ushort_t* __restrict__ vh,
    uchar_t* __restrict__ uq, uchar_t* __restrict__ vq, int N)
{
    __shared__ float At[NCH * NCH];   // At[k*32+c] = W[c][k] - W[c][32+k]
    __shared__ float Bt[NCH * NCH];   // Bt[k*32+c] = W[c][32+k]
    for (int i = threadIdx.x; i < NCH * NCH; i += 256) {
        const int k = i >> 5, c = i & 31;
        const float w1 = W[c * 64 + k];
        const float w2 = W[c * 64 + 32 + k];
        At[i] = w1 - w2;
        Bt[i] = w2;
    }
    __syncthreads();

    const int n = blockIdx.x * 8 + (threadIdx.x >> 5);
    const int c = threadIdx.x & 31;
    if (n >= N) return;

    const float xc = x[(size_t)n * NCH + c];
    float su = 0.f, sv = 0.f;
#pragma unroll
    for (int k = 0; k < NCH; ++k) {
        const float xk = __shfl(xc, k, 32);
        su = fmaf(At[k * 32 + c], xk, su);
        sv = fmaf(Bt[k * 32 + c], xk, sv);
    }
    uh[(size_t)n * NCH + c] = f2bf(su);
    vh[(size_t)n * NCH + c] = f2bf(sv);
    uq[(size_t)n * NCH + c] =
        (uchar_t)(__builtin_amdgcn_cvt_pk_fp8_f32(su, su, 0, false) & 0xFF);
    vq[(size_t)n * NCH + c] =
        (uchar_t)(__builtin_amdgcn_cvt_pk_fp8_f32(sv, sv, 0, false) & 0xFF);
}

// --- stats over fp8 copies: 16-lane group per edge, 2 channels per lane ----
__global__ __launch_bounds__(256) void k_stats8(
    const uchar_t* __restrict__ uq, const uchar_t* __restrict__ vq,
    const int* __restrict__ srci, const int* __restrict__ tgti,
    float* __restrict__ partials, int E)
{
    const ushort_t* __restrict__ uq16 = (const ushort_t*)uq;
    const ushort_t* __restrict__ vq16 = (const ushort_t*)vq;
    const int l  = threadIdx.x & 15;    // channel pair (2l, 2l+1)
    const int g  = (blockIdx.x * 256 + threadIdx.x) >> 4;
    const int nG = (gridDim.x * 256) >> 4;

    float s0 = 0.f, s1 = 0.f, q0 = 0.f, q1 = 0.f;
    int e = g;
    for (; e + 3 * nG < E; e += 4 * nG) {
        const int ea = e, eb = e + nG, ec = e + 2 * nG, ed = e + 3 * nG;
        const int sa = srci[ea], sb = srci[eb], sc = srci[ec], sd = srci[ed];
        const int ta = tgti[ea], tb = tgti[eb], tc = tgti[ec], td = tgti[ed];
        const ushort_t ua = uq16[(size_t)sa * 16 + l];
        const ushort_t ub = uq16[(size_t)sb * 16 + l];
        const ushort_t uc = uq16[(size_t)sc * 16 + l];
        const ushort_t ud = uq16[(size_t)sd * 16 + l];
        const ushort_t va = vq16[(size_t)ta * 16 + l];
        const ushort_t vb = vq16[(size_t)tb * 16 + l];
        const ushort_t vc = vq16[(size_t)tc * 16 + l];
        const ushort_t vd = vq16[(size_t)td * 16 + l];
#pragma unroll
        for (int k = 0; k < 4; ++k) {
            const ushort_t uu = (k == 0) ? ua : (k == 1) ? ub : (k == 2) ? uc : ud;
            const ushort_t vv = (k == 0) ? va : (k == 1) ? vb : (k == 2) ? vc : vd;
            const f32x2 uf = __builtin_amdgcn_cvt_pk_f32_fp8((int)uu, false);
            const f32x2 vf = __builtin_amdgcn_cvt_pk_f32_fp8((int)vv, false);
            const float y0 = uf.x + vf.x;
            const float y1 = uf.y + vf.y;
            s0 += y0; q0 = fmaf(y0, y0, q0);
            s1 += y1; q1 = fmaf(y1, y1, q1);
        }
    }
    for (; e < E; e += nG) {
        const int s = srci[e], t = tgti[e];
        const f32x2 uf = __builtin_amdgcn_cvt_pk_f32_fp8((int)uq16[(size_t)s * 16 + l], false);
        const f32x2 vf = __builtin_amdgcn_cvt_pk_f32_fp8((int)vq16[(size_t)t * 16 + l], false);
        const float y0 = uf.x + vf.x;
        const float y1 = uf.y + vf.y;
        s0 += y0; q0 = fmaf(y0, y0, q0);
        s1 += y1; q1 = fmaf(y1, y1, q1);
    }

    __shared__ float sL[16][32];
    __shared__ float qL[16][32];
    const int grp = threadIdx.x >> 4;
    sL[grp][2 * l + 0] = s0;
    sL[grp][2 * l + 1] = s1;
    qL[grp][2 * l + 0] = q0;
    qL[grp][2 * l + 1] = q1;
    __syncthreads();
    if (threadIdx.x < 32) {
        float a = 0.f;
#pragma unroll
        for (int r = 0; r < 16; ++r) a += sL[r][threadIdx.x];
        partials[(size_t)blockIdx.x * 64 + threadIdx.x] = a;
    } else if (threadIdx.x < 64) {
        const int cc = threadIdx.x - 32;
        float a = 0.f;
#pragma unroll
        for (int r = 0; r < 16; ++r) a += qL[r][cc];
        partials[(size_t)blockIdx.x * 64 + 32 + cc] = a;
    }
}

// --- combine partials -> BN affine a,b -------------------------------------
__global__ __launch_bounds__(256) void k_finalize(
    const float* __restrict__ partials, int nblocks,
    const float* __restrict__ gamma, const float* __restrict__ beta,
    float* __restrict__ ab, float invE)
{
    __shared__ float acc[4][64];
    const int vtx = threadIdx.x & 63, chunk = threadIdx.x >> 6;
    float s = 0.f;
    for (int r = chunk; r < nblocks; r += 4) s += partials[(size_t)r * 64 + vtx];
    acc[chunk][vtx] = s;
    __syncthreads();
    if (threadIdx.x < 64) acc[0][vtx] = acc[0][vtx] + acc[1][vtx] + acc[2][vtx] + acc[3][vtx];
    __syncthreads();
    if (threadIdx.x < 32) {
        const int c = threadIdx.x;
        float mean = acc[0][c] * invE;
        float var  = acc[0][32 + c] * invE - mean * mean;
        float rstd = rsqrtf(var + 1e-5f);
        float a = gamma[c] * rstd;
        ab[c] = a; ab[32 + c] = beta[c] - mean * a;
    }
}

// --- apply: 16-lane group per edge, packed bf16 atomic scatter -------------
__global__ __launch_bounds__(256) void k_apply_pk(
    const ushort_t* __restrict__ uh, const ushort_t* __restrict__ vh,
    const int* __restrict__ srci, const int* __restrict__ tgti,
    const float* __restrict__ ab,
    __hip_bfloat162* __restrict__ outh, int E)
{
    const uint_t* __restrict__ uh32 = (const uint_t*)uh;
    const uint_t* __restrict__ vh32 = (const uint_t*)vh;
    const int l  = threadIdx.x & 15;
    const float a0 = ab[2 * l + 0], a1 = ab[2 * l + 1];
    const float b0 = ab[32 + 2 * l + 0], b1 = ab[32 + 2 * l + 1];
    const int g  = (blockIdx.x * 256 + threadIdx.x) >> 4;
    const int nG = (gridDim.x * 256) >> 4;

    int e = g;
    for (; e + 3 * nG < E; e += 4 * nG) {
        const int ea = e, eb = e + nG, ec = e + 2 * nG, ed = e + 3 * nG;
        const int sa = srci[ea], sb = srci[eb], sc = srci[ec], sd = srci[ed];
        const int ta = tgti[ea], tb = tgti[eb], tc = tgti[ec], td = tgti[ed];
        const uint_t Ua = uh32[(size_t)sa * 16 + l];
        const uint_t Ub = uh32[(size_t)sb * 16 + l];
        const uint_t Uc = uh32[(size_t)sc * 16 + l];
        const uint_t Ud = uh32[(size_t)sd * 16 + l];
        const uint_t Va = vh32[(size_t)ta * 16 + l];
        const uint_t Vb = vh32[(size_t)tb * 16 + l];
        const uint_t Vc = vh32[(size_t)tc * 16 + l];
        const uint_t Vd = vh32[(size_t)td * 16 + l];
        const int ss[4] = {sa, sb, sc, sd};
        const uint_t UU[4] = {Ua, Ub, Uc, Ud};
        const uint_t VV[4] = {Va, Vb, Vc, Vd};
#pragma unroll
        for (int k = 0; k < 4; ++k) {
            const float y0 = bf2f((ushort_t)(UU[k] & 0xFFFF)) + bf2f((ushort_t)(VV[k] & 0xFFFF));
            const float y1 = bf2f((ushort_t)(UU[k] >> 16))    + bf2f((ushort_t)(VV[k] >> 16));
            float z0 = fmaf(a0, y0, b0);
            float z1 = fmaf(a1, y1, b1);
            z0 = (z0 > 0.f) ? z0 : (__expf(z0) - 1.0f);
            z1 = (z1 > 0.f) ? z1 : (__expf(z1) - 1.0f);
            pkAdd(&outh[(size_t)ss[k] * 16 + l], z0, z1);
        }
    }
    for (; e < E; e += nG) {
        const int s = srci[e], t = tgti[e];
        const uint_t U = uh32[(size_t)s * 16 + l];
        const uint_t V = vh32[(size_t)t * 16 + l];
        const float y0 = bf2f((ushort_t)(U & 0xFFFF)) + bf2f((ushort_t)(V & 0xFFFF));
        const float y1 = bf2f((ushort_t)(U >> 16))    + bf2f((ushort_t)(V >> 16));
        float z0 = fmaf(a0, y0, b0);
        float z1 = fmaf(a1, y1, b1);
        z0 = (z0 > 0.f) ? z0 : (__expf(z0) - 1.0f);
        z1 = (z1 > 0.f) ? z1 : (__expf(z1) - 1.0f);
        pkAdd(&outh[(size_t)s * 16 + l], z0, z1);
    }
}

// --- convert bf16 accumulator -> fp32 out ----------------------------------
__global__ __launch_bounds__(256) void k_cvt(
    const uint_t* __restrict__ outh32, float* __restrict__ out, int M)
{
    const int i = blockIdx.x * 256 + threadIdx.x;
    if (i >= M) return;
    const uint_t w = outh32[i];
    float2 f;
    f.x = bf2f((ushort_t)(w & 0xFFFF));
    f.y = bf2f((ushort_t)(w >> 16));
    ((float2*)out)[i] = f;
}

// ===========================================================================
// FALLBACK (round-1 proven path) — only if ws too small
// ===========================================================================
__global__ __launch_bounds__(256) void k_stats_hist(
    const float* __restrict__ x,
    const int* __restrict__ srci, const int* __restrict__ tgti,
    const float* __restrict__ W,
    float* __restrict__ partials, int E)
{
    float sum[NCH], ssq[NCH];
#pragma unroll
    for (int c = 0; c < NCH; ++c) { sum[c] = 0.f; ssq[c] = 0.f; }
    const int stride = gridDim.x * blockDim.x;
    for (int e = blockIdx.x * blockDim.x + threadIdx.x; e < E; e += stride) {
        const int s = srci[e], t = tgti[e];
        const float4* ps = (const float4*)(x + (size_t)s * NCH);
        const float4* pt = (const float4*)(x + (size_t)t * NCH);
        float xs[NCH], dx[NCH];
#pragma unroll
        for (int i = 0; i < 8; ++i) {
            float4 a = ps[i], bb = pt[i];
            xs[4*i+0] = a.x; xs[4*i+1] = a.y; xs[4*i+2] = a.z; xs[4*i+3] = a.w;
            dx[4*i+0] = bb.x - a.x; dx[4*i+1] = bb.y - a.y;
            dx[4*i+2] = bb.z - a.z; dx[4*i+3] = bb.w - a.w;
        }
#pragma unroll
        for (int c = 0; c < NCH; ++c) {
            const float* wr = W + c * 64;
            float y = 0.f;
#pragma unroll
            for (int k = 0; k < NCH; ++k) y = fmaf(wr[k], xs[k], y);
#pragma unroll
            for (int k = 0; k < NCH; ++k) y = fmaf(wr[32 + k], dx[k], y);
            sum[c] += y;
            ssq[c] = fmaf(y, y, ssq[c]);
        }
    }
#pragma unroll
    for (int c = 0; c < NCH; ++c) {
#pragma unroll
        for (int off = 32; off > 0; off >>= 1) {
            sum[c] += __shfl_down(sum[c], off);
            ssq[c] += __shfl_down(ssq[c], off);
        }
    }
    __shared__ float red[4][64];
    const int lane = threadIdx.x & 63, wave = threadIdx.x >> 6;
    if (lane == 0) {
#pragma unroll
        for (int c = 0; c < NCH; ++c) { red[wave][c] = sum[c]; red[wave][NCH+c] = ssq[c]; }
    }
    __syncthreads();
    if (threadIdx.x < 64)
        partials[(size_t)blockIdx.x * 64 + threadIdx.x] =
            red[0][threadIdx.x] + red[1][threadIdx.x] + red[2][threadIdx.x] + red[3][threadIdx.x];
}

__global__ __launch_bounds__(256) void k_apply_atomic(
    const float* __restrict__ x,
    const int* __restrict__ srci, const int* __restrict__ tgti,
    const float* __restrict__ W, const float* __restrict__ ab,
    float* __restrict__ out, int E)
{
    const int e = blockIdx.x * 256 + threadIdx.x;
    if (e >= E) return;
    const int s = srci[e], t = tgti[e];
    const float4* ps = (const float4*)(x + (size_t)s * NCH);
    const float4* pt = (const float4*)(x + (size_t)t * NCH);
    float xs[NCH], dx[NCH];
#pragma unroll
    for (int i = 0; i < 8; ++i) {
        float4 a = ps[i], bb = pt[i];
        xs[4*i+0] = a.x; xs[4*i+1] = a.y; xs[4*i+2] = a.z; xs[4*i+3] = a.w;
        dx[4*i+0] = bb.x - a.x; dx[4*i+1] = bb.y - a.y;
        dx[4*i+2] = bb.z - a.z; dx[4*i+3] = bb.w - a.w;
    }
    float* orow = out + (size_t)s * NCH;
#pragma unroll
    for (int c = 0; c < NCH; ++c) {
        const float* wr = W + c * 64;
        float y = 0.f;
#pragma unroll
        for (int k = 0; k < NCH; ++k) y = fmaf(wr[k], xs[k], y);
#pragma unroll
        for (int k = 0; k < NCH; ++k) y = fmaf(wr[32 + k], dx[k], y);
        float z = fmaf(ab[c], y, ab[32 + c]);
        z = (z > 0.f) ? z : (__expf(z) - 1.0f);
        atomicAdd(orow + c, z);
    }
}

// ===========================================================================
extern "C" void kernel_launch(void* const* d_in, const int* in_sizes, int n_in,
                              void* d_out, int out_size, void* d_ws, size_t ws_size,
                              hipStream_t stream)
{
    const float* x     = (const float*)d_in[0];
    const int*   ei    = (const int*)d_in[1];
    const float* W     = (const float*)d_in[2];
    const float* gamma = (const float*)d_in[3];
    const float* beta  = (const float*)d_in[4];
    const int E = in_sizes[1] / 2;
    const int N = in_sizes[0] / NCH;
    const int* srci = ei;
    const int* tgti = ei + E;

    const int SB = 1024;   // stats grid (16384 groups)
    const int AB = 2048;   // apply grid (32768 groups)

    // ws: uh,vh (bf16) | uq,vq (fp8) | outh (bf16) | partials | ab
    size_t need = (size_t)N * NCH * (2 + 2 + 1 + 1 + 2)
                + ((size_t)SB * 64 + 64) * 4;

    if (ws_size >= need) {
        ushort_t* uh      = (ushort_t*)d_ws;
        ushort_t* vh      = uh + (size_t)N * NCH;
        uchar_t*  uq      = (uchar_t*)(vh + (size_t)N * NCH);
        uchar_t*  vq      = uq + (size_t)N * NCH;
        __hip_bfloat162* outh = (__hip_bfloat162*)(vq + (size_t)N * NCH);
        float*    partials= (float*)((ushort_t*)outh + (size_t)N * NCH);
        float*    ab      = partials + (size_t)SB * 64;

        hipMemsetAsync(outh, 0, (size_t)N * NCH * 2, stream);
        k_uv3<<<(N + 7) / 8, 256, 0, stream>>>(x, W, uh, vh, uq, vq, N);
        k_stats8<<<SB, 256, 0, stream>>>(uq, vq, srci, tgti, partials, E);
        k_finalize<<<1, 256, 0, stream>>>(partials, SB, gamma, beta, ab, 1.0f / (float)E);
        k_apply_pk<<<AB, 256, 0, stream>>>(uh, vh, srci, tgti, ab, outh, E);
        k_cvt<<<(N * 16 + 255) / 256, 256, 0, stream>>>((const uint_t*)outh,
                                                        (float*)d_out, N * 16);
    } else {
        const int SBf = 512;
        float* ab       = (float*)d_ws;
        float* partials = ab + 64;
        hipMemsetAsync(d_out, 0, (size_t)out_size * sizeof(float), stream);
        k_stats_hist<<<SBf, 256, 0, stream>>>(x, srci, tgti, W, partials, E);
        k_finalize<<<1, 256, 0, stream>>>(partials, SBf, gamma, beta, ab, 1.0f / (float)E);
        k_apply_atomic<<<(E + 255) / 256, 256, 0, stream>>>(x, srci, tgti, W, ab,
                                                            (float*)d_out, E);
    }
}